// Round 7
// baseline (299.543 us; speedup 1.0000x reference)
//
#include <hip/hip_runtime.h>
#include <hip/hip_bf16.h>
#include <hip/hip_cooperative_groups.h>

namespace cg = cooperative_groups;

// HyperbolicMapper: LayerNorm -> spectral-norm linear (K=16) -> scale -> Poincare expmap0
// N=65536, D=4096, K=16. Memory-bound on reading x (1 GiB fp32).
// R6: single COOPERATIVE kernel. Blocks 0-15 (their waves 0-3) run the
// Gram-trick prep (gwb = bf16(gamma*W) remapped + 49 partials) into global ws;
// every block issues its first-iter x loads BEFORE the prep phase; grid.sync()
// replaces the prep->main kernel boundary (~4-5 us of HBM-idle time).
// Main loop identical to R5 (kk-remap, 64-col iters, per-wave rotation).

#define ND 4096
#define NK 16
#define NROWS 65536

using f32x4  = __attribute__((ext_vector_type(4))) float;
using bf16x8 = __attribute__((ext_vector_type(8))) short;

// workspace byte offsets
#define GWB_OFF  0u        // ushort[ND*NK] = 128 KB, gamma*W bf16, B-frag layout (remapped)
#define PART_OFF 131072u   // float[16*49]  : per-block partials (G16,B16,Mu16,uMu)

__device__ __forceinline__ unsigned short f2bf(float f) {
    union { __hip_bfloat16 h; unsigned short u; } cv;
    cv.h = __float2bfloat16(f);
    return cv.u;
}

// 256 blocks x 1024 threads, 1 block/CU (cooperative, all co-resident).
// A-frag (remapped): lane l (row=l&15, lc=l>>4), iter i covers cols i*64..i*64+63:
//   4 b128 loads at cols i*64 + lc*4 + {0,16,32,48}.
// B-frag: gwb LDS at ushort offset ss*512 + lane*8.
// C: col = lane&15 (k), row = (lane>>4)*4 + reg  [m89-verified].
__global__ __launch_bounds__(1024, 4) void hyp_coop(
    const float* __restrict__ x, const float* __restrict__ W,
    const float* __restrict__ gamma, const float* __restrict__ beta,
    const float* __restrict__ u, const float* __restrict__ log_scale,
    unsigned short* __restrict__ ws_gwb, float* __restrict__ ws_part,
    float* __restrict__ out)
{
    __shared__ unsigned short gwb[ND * NK];  // 128 KB
    __shared__ float wred[4][49];
    __shared__ float scl[49];

    const int tid  = threadIdx.x;
    const int lane = tid & 63;
    const int wid  = tid >> 6;
    const int tile = (blockIdx.x << 4) + wid;   // 0..4095, one per wave
    const int lr = lane & 15;                   // A-row within tile / C-col (k)
    const int lc = lane >> 4;                   // lane group

    const float* xp = x + (size_t)(tile * 16 + lr) * ND + lc * 4;
    const unsigned short* lp = gwb + lane * 8;  // + ss*512 ushorts per step
    const int start = (tile * 53) & 63;         // per-wave column rotation (64 iters)

    // issue first-iter x loads NOW; they stream while prep + grid.sync run
    const f32x4 xa0 = *(const f32x4*)(xp + start * 64);
    const f32x4 xb0 = *(const f32x4*)(xp + start * 64 + 16);
    const f32x4 xc0 = *(const f32x4*)(xp + start * 64 + 32);
    const f32x4 xd0 = *(const f32x4*)(xp + start * 64 + 48);

    // ================= distributed prep (blocks 0-15, waves 0-3) =================
    if (blockIdx.x < 16 && tid < 256) {
        const int d = blockIdx.x * 256 + tid;
        float uu[NK];
#pragma unroll
        for (int k = 0; k < NK; ++k) uu[k] = u[k];
        const float g = gamma[d], b = beta[d];
        float w[NK];
#pragma unroll
        for (int k = 0; k < NK; ++k) w[k] = W[k * ND + d];

        float t = 0.f;
#pragma unroll
        for (int k = 0; k < NK; ++k) t = fmaf(w[k], uu[k], t);

        // remapped B-frag layout: d -> (s, lc, j); slot = s*512 + lc*128 + k*8 + j
        const int s_  = d >> 5;
        const int wq  = d & 31;
        const int lcw = (wq >> 2) & 3;
        const int jw  = (wq & 3) | ((wq >> 4) << 2);
        const int base = s_ * 512 + lcw * 128 + jw;

        float P[49];
#pragma unroll
        for (int k = 0; k < NK; ++k) {
            const float gw = g * w[k];
            ws_gwb[base + k * 8] = f2bf(gw);
            P[k]      = gw;               // G
            P[16 + k] = b * w[k];         // B
            P[32 + k] = w[k] * t;         // Mu
        }
        P[48] = t * t;                    // uMu

#pragma unroll
        for (int m = 1; m < 64; m <<= 1) {
#pragma unroll
            for (int v = 0; v < 49; ++v) P[v] += __shfl_xor(P[v], m);
        }
        if (lane == 0) {
#pragma unroll
            for (int v = 0; v < 49; ++v) wred[tid >> 6][v] = P[v];
        }
    }
    __syncthreads();
    if (blockIdx.x < 16 && tid < 49)
        ws_part[blockIdx.x * 49 + tid] =
            (wred[0][tid] + wred[1][tid]) + (wred[2][tid] + wred[3][tid]);

    __threadfence();
    cg::this_grid().sync();

    // ================= stage gwb -> LDS + fold partials =================
    {
        const uint4* src = (const uint4*)ws_gwb;
        uint4* dst = (uint4*)gwb;
#pragma unroll
        for (int i = 0; i < 8; ++i)
            dst[tid + i * 1024] = src[tid + i * 1024];
    }
    if (tid < 49) {
        float s = 0.f;
#pragma unroll
        for (int b = 0; b < 16; ++b) s += ws_part[b * 49 + tid];
        scl[tid] = s;
    }
    __syncthreads();

    // sigma/coef, computed redundantly per thread (cheap)
    float ns2 = 0.f;
#pragma unroll
    for (int k = 0; k < NK; ++k) ns2 += scl[32 + k] * scl[32 + k];
    const float nt   = sqrtf(scl[48]) + 1e-12f;   // ||W^T u||
    const float nwv  = sqrtf(ns2) / nt;           // ||W v||
    const float sigma = (nwv * nwv) / (nwv + 1e-12f);
    const float coef = (0.5f / (1.0f + expf(-log_scale[0]))) / sigma;
    const float gk = scl[lr];        // G[k], k = lane&15 = C-col
    const float bk = scl[16 + lr];   // B[k]

    // ================= main loop over x =================
    f32x4 acc = {0.f, 0.f, 0.f, 0.f};
    float s1 = 0.f, s2 = 0.f;

#define HALF(XA, XB, SS) do {                                             \
        bf16x8 afrag;                                                     \
        afrag[0] = (short)f2bf(XA[0]); afrag[1] = (short)f2bf(XA[1]);     \
        afrag[2] = (short)f2bf(XA[2]); afrag[3] = (short)f2bf(XA[3]);     \
        afrag[4] = (short)f2bf(XB[0]); afrag[5] = (short)f2bf(XB[1]);     \
        afrag[6] = (short)f2bf(XB[2]); afrag[7] = (short)f2bf(XB[3]);     \
        s1 += ((XA[0] + XA[1]) + (XA[2] + XA[3]))                         \
            + ((XB[0] + XB[1]) + (XB[2] + XB[3]));                        \
        s2 = fmaf(XA[0], XA[0], s2); s2 = fmaf(XA[1], XA[1], s2);         \
        s2 = fmaf(XA[2], XA[2], s2); s2 = fmaf(XA[3], XA[3], s2);         \
        s2 = fmaf(XB[0], XB[0], s2); s2 = fmaf(XB[1], XB[1], s2);         \
        s2 = fmaf(XB[2], XB[2], s2); s2 = fmaf(XB[3], XB[3], s2);         \
        bf16x8 bfrag = *(const bf16x8*)(lp + (SS) * 512);                 \
        acc = __builtin_amdgcn_mfma_f32_16x16x32_bf16(afrag, bfrag, acc, 0, 0, 0); \
    } while (0)

#define PROCESS(II, XA, XB, XC, XD) do {                                  \
        HALF(XA, XB, 2 * (II));                                           \
        HALF(XC, XD, 2 * (II) + 1);                                       \
    } while (0)

#define LOADPROC(II) do {                                                 \
        f32x4 xa = *(const f32x4*)(xp + (II) * 64);                       \
        f32x4 xb = *(const f32x4*)(xp + (II) * 64 + 16);                  \
        f32x4 xc = *(const f32x4*)(xp + (II) * 64 + 32);                  \
        f32x4 xd = *(const f32x4*)(xp + (II) * 64 + 48);                  \
        PROCESS(II, xa, xb, xc, xd);                                      \
    } while (0)

    PROCESS(start, xa0, xb0, xc0, xd0);
#pragma unroll 2
    for (int i = start + 1; i < 64; ++i) LOADPROC(i);
#pragma unroll 2
    for (int i = 0; i < start; ++i) LOADPROC(i);
#undef LOADPROC
#undef PROCESS
#undef HALF

    // S1/S2 for row lr: reduce across the 4 lanes {l, l^16, l^32, l^48}
    s1 += __shfl_xor(s1, 16); s1 += __shfl_xor(s1, 32);
    s2 += __shfl_xor(s2, 16); s2 += __shfl_xor(s2, 32);
    const float mean = s1 * (1.0f / ND);
    const float var  = s2 * (1.0f / ND) - mean * mean;
    const float rstd = rsqrtf(var + 1e-5f);

    float vout[4];
#pragma unroll
    for (int j = 0; j < 4; ++j) {
        const int r = lc * 4 + j;              // C-row within tile
        const float m_r  = __shfl(mean, r);    // stats live in lane r (r<16)
        const float rs_r = __shfl(rstd, r);
        vout[j] = coef * (fmaf(-m_r, gk, acc[j]) * rs_r + bk);
    }

    // row-norm over k: reduce across the 16 lanes sharing lc (xor masks 1,2,4,8)
    float nsq[4];
#pragma unroll
    for (int j = 0; j < 4; ++j) nsq[j] = vout[j] * vout[j];
#pragma unroll
    for (int m = 1; m < 16; m <<= 1) {
#pragma unroll
        for (int j = 0; j < 4; ++j) nsq[j] += __shfl_xor(nsq[j], m);
    }

#pragma unroll
    for (int j = 0; j < 4; ++j) {
        float nv = sqrtf(nsq[j]);
        nv = fmaxf(nv, 1e-15f);
        const float fac = tanhf(nv) / nv;
        out[(size_t)(tile * 16 + lc * 4 + j) * NK + lr] = vout[j] * fac;
    }
}

extern "C" void kernel_launch(void* const* d_in, const int* in_sizes, int n_in,
                              void* d_out, int out_size, void* d_ws, size_t ws_size,
                              hipStream_t stream) {
    const float* x     = (const float*)d_in[0];
    const float* gamma = (const float*)d_in[1];
    const float* beta  = (const float*)d_in[2];
    const float* W     = (const float*)d_in[3];
    const float* u     = (const float*)d_in[4];
    const float* ls    = (const float*)d_in[5];

    char* ws = (char*)d_ws;
    unsigned short* ws_gwb = (unsigned short*)(ws + GWB_OFF);
    float* ws_part = (float*)(ws + PART_OFF);
    float* out     = (float*)d_out;

    void* args[] = {
        (void*)&x, (void*)&W, (void*)&gamma, (void*)&beta, (void*)&u,
        (void*)&ls, (void*)&ws_gwb, (void*)&ws_part, (void*)&out
    };
    hipLaunchCooperativeKernel((const void*)hyp_coop, dim3(256), dim3(1024),
                               args, 0, stream);
}

// Round 8
// 188.051 us; speedup vs baseline: 1.5929x; 1.5929x over previous
//
#include <hip/hip_runtime.h>
#include <hip/hip_bf16.h>

// HyperbolicMapper: LayerNorm -> spectral-norm linear (K=16) -> scale -> Poincare expmap0
// N=65536, D=4096, K=16. Memory-bound on reading x (1 GiB fp32).
// R7: occupancy probe. gwb (B-fragments) evicted from LDS -> read straight
// from L2 (1 KB/wave/step, per-XCD resident). LDS ~0 => 1024 blocks x 256 thr,
// __launch_bounds__(256,8) targeting <=64 VGPR => 32 waves/CU (2x R5) to hide
// DRAM page/bank stalls. 32-col steps, 128-phase rotation. Prep = R5 Gram trick.

#define ND 4096
#define NK 16
#define NROWS 65536

using f32x4  = __attribute__((ext_vector_type(4))) float;
using bf16x8 = __attribute__((ext_vector_type(8))) short;

// workspace byte offsets
#define GWB_OFF  0u        // ushort[ND*NK] = 128 KB, gamma*W bf16, B-frag layout (remapped)
#define PART_OFF 131072u   // float[16*49]  : per-block partials (G16,B16,Mu16,uMu)

__device__ __forceinline__ unsigned short f2bf(float f) {
    union { __hip_bfloat16 h; unsigned short u; } cv;
    cv.h = __float2bfloat16(f);
    return cv.u;
}

// ---------------- prep: one pass over W (16 blocks x 256 thr) ----------------
// thread <-> column d: t = w.u; Mu[k] += w[k]*t; uMu += t^2; G/B partials;
// writes bf16(gamma*W) in remapped B-frag layout.
__global__ __launch_bounds__(256) void prep(
    const float* __restrict__ W, const float* __restrict__ gamma,
    const float* __restrict__ beta, const float* __restrict__ u,
    unsigned short* __restrict__ ws_gwb, float* __restrict__ ws_part)
{
    const int tid = threadIdx.x;
    const int d = blockIdx.x * 256 + tid;
    const int lane = tid & 63, wid = tid >> 6;

    float uu[NK];
#pragma unroll
    for (int k = 0; k < NK; ++k) uu[k] = u[k];
    const float g = gamma[d], b = beta[d];
    float w[NK];
#pragma unroll
    for (int k = 0; k < NK; ++k) w[k] = W[k * ND + d];

    float t = 0.f;
#pragma unroll
    for (int k = 0; k < NK; ++k) t = fmaf(w[k], uu[k], t);

    // remapped B-frag layout: d -> (s, lc, j); slot = s*512 + lc*128 + k*8 + j
    const int s  = d >> 5;
    const int wq = d & 31;
    const int lc = (wq >> 2) & 3;
    const int j  = (wq & 3) | ((wq >> 4) << 2);
    const int base = s * 512 + lc * 128 + j;

    float P[49];
#pragma unroll
    for (int k = 0; k < NK; ++k) {
        const float gw = g * w[k];
        ws_gwb[base + k * 8] = f2bf(gw);
        P[k]      = gw;               // G
        P[16 + k] = b * w[k];         // B
        P[32 + k] = w[k] * t;         // Mu
    }
    P[48] = t * t;                    // uMu

    // wave butterfly reduce all 49
#pragma unroll
    for (int m = 1; m < 64; m <<= 1) {
#pragma unroll
        for (int v = 0; v < 49; ++v) P[v] += __shfl_xor(P[v], m);
    }
    __shared__ float wred[4][49];
    if (lane == 0) {
#pragma unroll
        for (int v = 0; v < 49; ++v) wred[wid][v] = P[v];
    }
    __syncthreads();
    if (tid < 49)
        ws_part[blockIdx.x * 49 + tid] =
            (wred[0][tid] + wred[1][tid]) + (wred[2][tid] + wred[3][tid]);
}

// ---------------- main: one pass over x, MFMA 16x16x32 bf16 ----------------
// 1024 blocks x 256 threads; 4 waves/block; wave <-> one 16-row tile.
// A-frag (remapped): lane l (row=l&15, lc=l>>4), step s:
//   xa = x[row][s*32 + lc*4 .. +3], xb = x[row][s*32 + 16 + lc*4 ..]
// B-frag: read DIRECTLY from global ws_gwb at ushort offset s*512 + lane*8
//   (L2-resident, 1 KB/wave/step).
// C: col = lane&15 (k), row = (lane>>4)*4 + reg  [m89-verified].
// K-loop rotated per wave at step granularity (128 phases).
__global__ __launch_bounds__(256, 8) void hyp_main(
    const float* __restrict__ x, const unsigned short* __restrict__ gwb_g,
    const float* __restrict__ ws_part, const float* __restrict__ log_scale,
    float* __restrict__ out)
{
    __shared__ float scl[49];

    const int tid  = threadIdx.x;
    const int lane = tid & 63;
    const int wid  = tid >> 6;                  // 0..3
    const int tile = (blockIdx.x << 2) + wid;   // 0..4095, one per wave
    const int lr = lane & 15;                   // A-row within tile / C-col (k)
    const int lc = lane >> 4;                   // lane group

    const float* xp = x + (size_t)(tile * 16 + lr) * ND + lc * 4;
    const unsigned short* bp = gwb_g + lane * 8;  // + s*512 ushorts per step
    const int start = (tile * 53) & 127;          // per-wave rotation, step granularity

    // issue first-step loads NOW; they complete under the partial fold
    const f32x4 xa0 = *(const f32x4*)(xp + start * 32);
    const f32x4 xb0 = *(const f32x4*)(xp + start * 32 + 16);
    const bf16x8 bf0 = *(const bf16x8*)(bp + start * 512);

    // fold the 16 per-block prep partials (tiny)
    if (tid < 49) {
        float s = 0.f;
#pragma unroll
        for (int b = 0; b < 16; ++b) s += ws_part[b * 49 + tid];
        scl[tid] = s;
    }
    __syncthreads();

    // sigma/coef, computed redundantly per thread (cheap)
    float ns2 = 0.f;
#pragma unroll
    for (int k = 0; k < NK; ++k) ns2 += scl[32 + k] * scl[32 + k];
    const float nt   = sqrtf(scl[48]) + 1e-12f;   // ||W^T u||
    const float nwv  = sqrtf(ns2) / nt;           // ||W v||
    const float sigma = (nwv * nwv) / (nwv + 1e-12f);
    const float coef = (0.5f / (1.0f + expf(-log_scale[0]))) / sigma;
    const float gk = scl[lr];        // G[k], k = lane&15 = C-col
    const float bk = scl[16 + lr];   // B[k]

    // ================= main loop over x =================
    f32x4 acc = {0.f, 0.f, 0.f, 0.f};
    float s1 = 0.f, s2 = 0.f;

#define PROC_BODY(XA, XB, BF) do {                                        \
        bf16x8 afrag;                                                     \
        afrag[0] = (short)f2bf(XA[0]); afrag[1] = (short)f2bf(XA[1]);     \
        afrag[2] = (short)f2bf(XA[2]); afrag[3] = (short)f2bf(XA[3]);     \
        afrag[4] = (short)f2bf(XB[0]); afrag[5] = (short)f2bf(XB[1]);     \
        afrag[6] = (short)f2bf(XB[2]); afrag[7] = (short)f2bf(XB[3]);     \
        s1 += ((XA[0] + XA[1]) + (XA[2] + XA[3]))                         \
            + ((XB[0] + XB[1]) + (XB[2] + XB[3]));                        \
        s2 = fmaf(XA[0], XA[0], s2); s2 = fmaf(XA[1], XA[1], s2);         \
        s2 = fmaf(XA[2], XA[2], s2); s2 = fmaf(XA[3], XA[3], s2);         \
        s2 = fmaf(XB[0], XB[0], s2); s2 = fmaf(XB[1], XB[1], s2);         \
        s2 = fmaf(XB[2], XB[2], s2); s2 = fmaf(XB[3], XB[3], s2);         \
        acc = __builtin_amdgcn_mfma_f32_16x16x32_bf16(afrag, (BF), acc, 0, 0, 0); \
    } while (0)

#define PROCESS(SS) do {                                                  \
        f32x4 xa = *(const f32x4*)(xp + (SS) * 32);                       \
        f32x4 xb = *(const f32x4*)(xp + (SS) * 32 + 16);                  \
        bf16x8 bfr = *(const bf16x8*)(bp + (SS) * 512);                   \
        PROC_BODY(xa, xb, bfr);                                           \
    } while (0)

    PROC_BODY(xa0, xb0, bf0);
#pragma unroll 2
    for (int s = start + 1; s < 128; ++s) PROCESS(s);
#pragma unroll 2
    for (int s = 0; s < start; ++s) PROCESS(s);
#undef PROCESS
#undef PROC_BODY

    // S1/S2 for row lr: reduce across the 4 lanes {l, l^16, l^32, l^48}
    s1 += __shfl_xor(s1, 16); s1 += __shfl_xor(s1, 32);
    s2 += __shfl_xor(s2, 16); s2 += __shfl_xor(s2, 32);
    const float mean = s1 * (1.0f / ND);
    const float var  = s2 * (1.0f / ND) - mean * mean;
    const float rstd = rsqrtf(var + 1e-5f);

    float vout[4];
#pragma unroll
    for (int j = 0; j < 4; ++j) {
        const int r = lc * 4 + j;              // C-row within tile
        const float m_r  = __shfl(mean, r);    // stats live in lane r (r<16)
        const float rs_r = __shfl(rstd, r);
        vout[j] = coef * (fmaf(-m_r, gk, acc[j]) * rs_r + bk);
    }

    // row-norm over k: reduce across the 16 lanes sharing lc (xor masks 1,2,4,8)
    float nsq[4];
#pragma unroll
    for (int j = 0; j < 4; ++j) nsq[j] = vout[j] * vout[j];
#pragma unroll
    for (int m = 1; m < 16; m <<= 1) {
#pragma unroll
        for (int j = 0; j < 4; ++j) nsq[j] += __shfl_xor(nsq[j], m);
    }

#pragma unroll
    for (int j = 0; j < 4; ++j) {
        float nv = sqrtf(nsq[j]);
        nv = fmaxf(nv, 1e-15f);
        const float fac = tanhf(nv) / nv;
        out[(size_t)(tile * 16 + lc * 4 + j) * NK + lr] = vout[j] * fac;
    }
}

extern "C" void kernel_launch(void* const* d_in, const int* in_sizes, int n_in,
                              void* d_out, int out_size, void* d_ws, size_t ws_size,
                              hipStream_t stream) {
    const float* x     = (const float*)d_in[0];
    const float* gamma = (const float*)d_in[1];
    const float* beta  = (const float*)d_in[2];
    const float* W     = (const float*)d_in[3];
    const float* u     = (const float*)d_in[4];
    const float* ls    = (const float*)d_in[5];

    char* ws = (char*)d_ws;
    unsigned short* ws_gwb = (unsigned short*)(ws + GWB_OFF);
    float* ws_part = (float*)(ws + PART_OFF);
    float* out     = (float*)d_out;

    prep<<<16, 256, 0, stream>>>(W, gamma, beta, u, ws_gwb, ws_part);
    hyp_main<<<1024, 256, 0, stream>>>(x, ws_gwb, ws_part, ls, out);
}